// Round 4
// baseline (775.857 us; speedup 1.0000x reference)
//
#include <hip/hip_runtime.h>
#include <cstdint>
#include <math.h>

#define NCLS  20
#define MSZ   512
#define DIM   256
#define HW    16384      // 128*128
#define NPIX  131072     // 4 * 2 * 16384
#define AROWS 10240      // NCLS * MSZ
#define TEMP_INV 10.0f
#define EXP2K 14.4269504088896f   // TEMP_INV * log2(e)

typedef __attribute__((ext_vector_type(8))) short bf16x8;
typedef __attribute__((ext_vector_type(4))) float f32x4;

__device__ __forceinline__ short f2bf(float f) {
    unsigned u = __float_as_uint(f);
    unsigned r = (u + 0x7FFFu + ((u >> 16) & 1u)) >> 16;
    return (short)r;
}
__device__ __forceinline__ float bf2f(short s) {
    return __uint_as_float(((unsigned)(unsigned short)s) << 16);
}
__device__ __forceinline__ float fexp2(float x) {
    float r;
    asm volatile("v_exp_f32 %0, %1" : "=v"(r) : "v"(x));
    return r;
}
// async global->LDS, 16B/lane, wave-uniform LDS base + lane*16
__device__ __forceinline__ void gld16(const void* g, void* l) {
    __builtin_amdgcn_global_load_lds(
        (const __attribute__((address_space(1))) unsigned int*)(uintptr_t)g,
        (__attribute__((address_space(3))) unsigned int*)(unsigned int)(uintptr_t)l,
        16, 0, 0);
}

// zero-region float layout (15488 floats = 61952 B):
//   [0]       row_sumexp   (10240)
//   [10240]   S            (5120)
//   [15360]   pcnt         (20 ints)
//   [15380]   facc[2]      (loss sum, valid count)
//   [15382]   done_cnt     (int)
#define ZREG_FLOATS 15488

// ---------------- K1: labels + per-chunk class histogram + inits (no cross-block races) ----------------
__global__ __launch_bounds__(256) void k_hist(const int* __restrict__ mg,
                                              const int* __restrict__ ag,
                                              int* __restrict__ labels,
                                              int* __restrict__ hist,
                                              int* __restrict__ pix2row,
                                              float* __restrict__ zreg) {
    int chunk = blockIdx.x, t = threadIdx.x;
    int lane = t & 63;
    int gi = chunk * 256 + t;
    if (gi < ZREG_FLOATS) zreg[gi] = 0.0f;

    int n = gi;
    int b = n >> 15, r = n & 32767;
    const int* g = (r < HW) ? mg : ag;
    int p = (r < HW) ? r : (r - HW);
    int h = p >> 7, w = p & 127;
    int lab = g[(((size_t)b * 512) + (size_t)(h << 2)) * 512 + (size_t)(w << 2)];
    if (lab == 255) lab = -1;
    else if (lab == 254) lab = NCLS - 1;
    labels[n] = lab;
    pix2row[n] = -1;

    __shared__ int cnt20[NCLS];
    if (t < NCLS) cnt20[t] = 0;
    __syncthreads();
#pragma unroll
    for (int c = 0; c < NCLS; ++c) {
        unsigned long long m = __ballot(lab == c);
        if (lane == 0 && m) atomicAdd(&cnt20[c], __popcll(m));
    }
    __syncthreads();
    if (t < NCLS) hist[t * 512 + chunk] = cnt20[t];
}

// ---------------- K2: deterministic ordered compaction -> pix2row; last chunk writes counts ----------------
__global__ __launch_bounds__(256) void k_write(const int* __restrict__ labels,
                                               const int* __restrict__ hist,
                                               int* __restrict__ pix2row,
                                               int* __restrict__ counts) {
    int chunk = blockIdx.x, t = threadIdx.x;
    int lane = t & 63, wv = t >> 6;
    __shared__ int cbase[NCLS];
    __shared__ int wcnt2[4][NCLS];

#pragma unroll
    for (int cc = 0; cc < 5; ++cc) {
        int c = wv * 5 + cc;
        int s = 0;
        for (int j = lane; j < chunk; j += 64) s += hist[c * 512 + j];
#pragma unroll
        for (int o = 32; o > 0; o >>= 1) s += __shfl_down(s, o, 64);
        if (lane == 0) cbase[c] = s;
    }

    int n = chunk * 256 + t;
    int lab = labels[n];
    int myrank = 0;
#pragma unroll
    for (int c = 0; c < NCLS; ++c) {
        unsigned long long m = __ballot(lab == c);
        if (lane == 0) wcnt2[wv][c] = __popcll(m);
        if (lab == c) myrank = __popcll(m & ((1ull << lane) - 1ull));
    }
    __syncthreads();
    if (lab >= 0) {
        int base = cbase[lab] + myrank;
        for (int w = 0; w < wv; ++w) base += wcnt2[w][lab];
        if (base < MSZ) pix2row[n] = lab * MSZ + base;
    }
    // chunk 511: total count per class = prefix + own chunk (race-free, no atomics)
    if (chunk == 511 && t < NCLS)
        counts[t] = cbase[t] + wcnt2[0][t] + wcnt2[1][t] + wcnt2[2][t] + wcnt2[3][t];
}

// ---------------- K3: pix2row-first conditional read of proj, scatter selected to xF ----------------
// Only ~8% of pixels are selected; load the (L2-resident) pix2row int4 FIRST and skip the
// 16B proj load when all four lanes' rows are -1 -> HBM read traffic drops ~10x.
__global__ __launch_bounds__(256) void k_scatter(const float* __restrict__ mainp,
                                                 const float* __restrict__ auxp,
                                                 const int* __restrict__ pix2row,
                                                 float* __restrict__ xF) {
    int idx = blockIdx.x * 256 + threadIdx.x;
    int p4 = idx & 4095;
    int ch = (idx >> 12) & 255;
    int bs = idx >> 20;                          // 0..7 = b*2+src
    int b = bs >> 1, src = bs & 1;
    int4 pr = *(const int4*)(pix2row + bs * HW + p4 * 4);
    if ((pr.x & pr.y & pr.z & pr.w) < 0) return; // all four negative -> nothing selected
    const float* base = (src ? auxp : mainp) + (size_t)b * DIM * HW + (size_t)ch * HW;
    float4 v = *(const float4*)(base + p4 * 4);
    if (pr.x >= 0) xF[(size_t)pr.x * DIM + ch] = v.x;
    if (pr.y >= 0) xF[(size_t)pr.y * DIM + ch] = v.y;
    if (pr.z >= 0) xF[(size_t)pr.z * DIM + ch] = v.z;
    if (pr.w >= 0) xF[(size_t)pr.w * DIM + ch] = v.w;
}

// ---------------- K4: fused normalize + bank update + per-class S/pcnt ----------------
// block = 64 rows of one class (160 blocks); wave handles 16 rows (4 consecutive rows / iter)
__global__ __launch_bounds__(256) void k_nbc(const float* __restrict__ xF,
                                             const float* __restrict__ bank,
                                             const int* __restrict__ counts,
                                             short* __restrict__ anchorsB,
                                             short* __restrict__ contrasB,
                                             int* __restrict__ c_valid,
                                             float* __restrict__ S,
                                             int* __restrict__ pcnt) {
    int blk = blockIdx.x;
    int c = blk >> 3;
    int t = threadIdx.x, lane = t & 63, wv = t >> 6;
    int cc = counts[c];
    int base = blk * 64;
    float sacc[4] = {0.f, 0.f, 0.f, 0.f};
    int vcnt = 0;

    for (int it = 0; it < 16; ++it) {
        int a = base + it * 4 + wv;
        int m = a & 511;
        float4 xv = *(const float4*)&xF[(size_t)a * DIM + lane * 4];
        float x[4] = {xv.x, xv.y, xv.z, xv.w};
        float ss = x[0]*x[0] + x[1]*x[1] + x[2]*x[2] + x[3]*x[3];
#pragma unroll
        for (int o = 1; o < 64; o <<= 1) ss += __shfl_xor(ss, o, 64);
        float scale = 1.0f / fmaxf(sqrtf(ss), 1e-12f);
        float ax[4];
#pragma unroll
        for (int q = 0; q < 4; ++q) ax[q] = x[q] * scale;
        short4 oa;
        oa.x = f2bf(ax[0]); oa.y = f2bf(ax[1]); oa.z = f2bf(ax[2]); oa.w = f2bf(ax[3]);
        *(short4*)&anchorsB[(size_t)a * DIM + lane * 4] = oa;

        bool upd = m < cc;
        float4 bv = *(const float4*)&bank[(size_t)a * DIM + lane * 4];
        float u[4];
        u[0] = upd ? 0.999f * bv.x + 0.001f * ax[0] : bv.x;
        u[1] = upd ? 0.999f * bv.y + 0.001f * ax[1] : bv.y;
        u[2] = upd ? 0.999f * bv.z + 0.001f * ax[2] : bv.z;
        u[3] = upd ? 0.999f * bv.w + 0.001f * ax[3] : bv.w;
        float ss2 = u[0]*u[0] + u[1]*u[1] + u[2]*u[2] + u[3]*u[3];
#pragma unroll
        for (int o = 1; o < 64; o <<= 1) ss2 += __shfl_xor(ss2, o, 64);
        float nrm = sqrtf(ss2);
        float inv = 1.0f / fmaxf(nrm, 1e-12f);
        short oc[4];
        oc[0] = f2bf(upd ? u[0] * inv : bv.x);
        oc[1] = f2bf(upd ? u[1] * inv : bv.y);
        oc[2] = f2bf(upd ? u[2] * inv : bv.z);
        oc[3] = f2bf(upd ? u[3] * inv : bv.w);
        *(short4*)&contrasB[(size_t)a * DIM + lane * 4] = *(short4*)oc;
        bool valid = nrm > 0.0f;
        if (lane == 0) {
            c_valid[a] = valid ? 1 : 0;
            vcnt += valid ? 1 : 0;
        }
        if (valid) {
#pragma unroll
            for (int q = 0; q < 4; ++q) sacc[q] += bf2f(oc[q]);
        }
    }

    __shared__ float s4[4][DIM];
    __shared__ int pv[4];
#pragma unroll
    for (int q = 0; q < 4; ++q) s4[wv][lane * 4 + q] = sacc[q];
    if (lane == 0) pv[wv] = vcnt;
    __syncthreads();
    float s = s4[0][t] + s4[1][t] + s4[2][t] + s4[3][t];
    atomicAdd(&S[c * DIM + t], s);
    if (t == 0) atomicAdd(&pcnt[c], pv[0] + pv[1] + pv[2] + pv[3]);
}

// ---------------- K5: bf16 MFMA scores + fused sum-exp (v4: 3 blocks/CU) ----------------
// Same structure as v3 (128x256 tile, 8 waves of 64x64, BK=64 single-buffer, 48 KiB LDS,
// 2 barriers/K-tile, full XOR swizzle = 0 conflicts) but __launch_bounds__(512,6) ->
// 3 blocks/CU (144 KiB LDS, 24 waves/CU): one more independent block per CU to fill the
// per-K-tile barrier stalls. v3's arithmetic: MFMA content ~6.9us of a 12.5us 2-block slot
// (28% MfmaUtil) -> +50% resident work should lift util toward ~40%.
__global__ __launch_bounds__(512, 6) void k_score(const short* __restrict__ A,
                                                  const short* __restrict__ Bc,
                                                  const int* __restrict__ c_valid,
                                                  float* __restrict__ row_sumexp) {
    __shared__ short As[128 * 64];   // 16 KiB
    __shared__ short Bs[256 * 64];   // 32 KiB
    const int t = threadIdx.x;
    const int lane = t & 63, wv = t >> 6;
    const int wr = wv & 1, wc = wv >> 1;    // wave tile: rows wr*64..+64, cols wc*64..+64
    const int qr = lane >> 4, qc = lane & 15;
    const int s7 = qc & 7;
    const int row0 = blockIdx.x * 128, col0 = blockIdx.y * 256;

    // staging: thread t covers row rl8 = t>>3 of each 64-row chunk, linear slot t&7.
    // source fetches data slot sdat = (t&7)^(row&7) so LDS(row, slot) holds data slot^(row&7).
    const int rl8 = t >> 3;
    const int sdat = (t & 7) ^ (rl8 & 7);
    const short* Ag = A  + (size_t)row0 * DIM;
    const short* Bg = Bc + (size_t)col0 * DIM;

    // frag-read slot offsets (shorts): data slot kk*4+qr lives at ((kk*4+qr)^(row&7)),
    // row&7 == qc&7 for all fragment rows (row = mult8 + qc).
    const int sl0 = ((0 + qr) ^ s7) * 8;
    const int sl1 = ((4 + qr) ^ s7) * 8;

    f32x4 acc[4][4] = {};                   // [rt][ct]

    auto stage = [&](int kt) {
#pragma unroll
        for (int r = 0; r < 2; ++r)
            gld16(Ag + (size_t)(r * 64 + rl8) * DIM + kt * 64 + sdat * 8,
                  &As[(r * 64 + wv * 8) * 64]);
#pragma unroll
        for (int r = 0; r < 4; ++r)
            gld16(Bg + (size_t)(r * 64 + rl8) * DIM + kt * 64 + sdat * 8,
                  &Bs[(r * 64 + wv * 8) * 64]);
    };

    stage(0);
    for (int kt = 0; kt < 4; ++kt) {
        asm volatile("s_waitcnt vmcnt(0)" ::: "memory");   // stage(kt) landed (issued 1 tile ago)
        asm volatile("s_barrier" ::: "memory");            // buffer ready for all waves

        bf16x8 a0[4], b0[4], a1[4], b1[4];
#pragma unroll
        for (int rt = 0; rt < 4; ++rt)
            a0[rt] = *(const bf16x8*)&As[(wr * 64 + rt * 16 + qc) * 64 + sl0];
#pragma unroll
        for (int ct = 0; ct < 4; ++ct)
            b0[ct] = *(const bf16x8*)&Bs[(wc * 64 + ct * 16 + qc) * 64 + sl0];
#pragma unroll
        for (int rt = 0; rt < 4; ++rt)
#pragma unroll
            for (int ct = 0; ct < 4; ++ct)
                acc[rt][ct] = __builtin_amdgcn_mfma_f32_16x16x32_bf16(a0[rt], b0[ct], acc[rt][ct], 0, 0, 0);
#pragma unroll
        for (int rt = 0; rt < 4; ++rt)
            a1[rt] = *(const bf16x8*)&As[(wr * 64 + rt * 16 + qc) * 64 + sl1];
#pragma unroll
        for (int ct = 0; ct < 4; ++ct)
            b1[ct] = *(const bf16x8*)&Bs[(wc * 64 + ct * 16 + qc) * 64 + sl1];

        asm volatile("s_waitcnt lgkmcnt(0)" ::: "memory"); // all my ds_reads complete
        __builtin_amdgcn_sched_barrier(0);                 // (rule 18) nothing hoists above
        asm volatile("s_barrier" ::: "memory");            // all waves done reading buffer
        if (kt < 3) stage(kt + 1);                         // async overwrite, lands during MFMA+next wait

#pragma unroll
        for (int rt = 0; rt < 4; ++rt)
#pragma unroll
            for (int ct = 0; ct < 4; ++ct)
                acc[rt][ct] = __builtin_amdgcn_mfma_f32_16x16x32_bf16(a1[rt], b1[ct], acc[rt][ct], 0, 0, 0);
    }

    // fused masked sum-exp epilogue: per row-partial over this block's 256 cols
    float cm[4];
#pragma unroll
    for (int ct = 0; ct < 4; ++ct)
        cm[ct] = c_valid[col0 + wc * 64 + ct * 16 + qc] ? 1.0f : 0.0f;
#pragma unroll
    for (int rt = 0; rt < 4; ++rt)
#pragma unroll
        for (int r = 0; r < 4; ++r) {
            float e = cm[0] * fexp2(acc[rt][0][r] * EXP2K)
                    + cm[1] * fexp2(acc[rt][1][r] * EXP2K)
                    + cm[2] * fexp2(acc[rt][2][r] * EXP2K)
                    + cm[3] * fexp2(acc[rt][3][r] * EXP2K);
#pragma unroll
            for (int o = 1; o < 16; o <<= 1) e += __shfl_xor(e, o, 64);
            if (qc == 0)
                atomicAdd(&row_sumexp[row0 + wr * 64 + rt * 16 + qr * 4 + r], e);
        }
}

// ---------------- K6: per-row loss terms + last-block final reduction ----------------
// block = 64 rows (160 blocks); pos_sum = TEMP_INV * (anchor . S[class])
__global__ __launch_bounds__(256) void k_fin(const short* __restrict__ anchorsB,
                                             const float* __restrict__ S,
                                             const int* __restrict__ counts,
                                             const int* __restrict__ pcnt,
                                             const float* __restrict__ row_sumexp,
                                             float* __restrict__ facc,
                                             int* __restrict__ done_cnt,
                                             float* __restrict__ out) {
    int blk = blockIdx.x;
    int c = blk >> 3;
    int t = threadIdx.x, lane = t & 63, wv = t >> 6;
    int pc = pcnt[c], cc = counts[c];
    float lsum = 0.0f, vc = 0.0f;

    for (int it = 0; it < 16; ++it) {
        int a = blk * 64 + it * 4 + wv;
        short4 a4 = *(const short4*)&anchorsB[(size_t)a * DIM + lane * 4];
        float4 s4 = *(const float4*)&S[c * DIM + lane * 4];
        float dot = bf2f(a4.x) * s4.x + bf2f(a4.y) * s4.y
                  + bf2f(a4.z) * s4.z + bf2f(a4.w) * s4.w;
#pragma unroll
        for (int o = 1; o < 64; o <<= 1) dot += __shfl_xor(dot, o, 64);
        if (lane == 0 && (a & 511) < cc && pc > 0) {
            float lse = logf(row_sumexp[a]);
            lsum += (TEMP_INV * dot - (float)pc * lse) / (float)pc;
            vc += 1.0f;
        }
    }

    __shared__ float wls[4], wvc[4];
    if (lane == 0) { wls[wv] = lsum; wvc[wv] = vc; }
    __syncthreads();
    if (t == 0) {
        atomicAdd(&facc[0], wls[0] + wls[1] + wls[2] + wls[3]);
        atomicAdd(&facc[1], wvc[0] + wvc[1] + wvc[2] + wvc[3]);
        __threadfence();
        unsigned d = atomicAdd((unsigned*)done_cnt, 1u);
        if (d == 159u) {   // last block: totals are globally visible via atomics
            __threadfence();
            float L = atomicAdd(&facc[0], 0.0f);
            float V = atomicAdd(&facc[1], 0.0f);
            out[0] = -L / fmaxf(V, 1.0f);
        }
    }
}

// ---------------- launch ----------------
extern "C" void kernel_launch(void* const* d_in, const int* in_sizes, int n_in,
                              void* d_out, int out_size, void* d_ws, size_t ws_size,
                              hipStream_t stream) {
    const float* main_proj = (const float*)d_in[0];
    const int*   main_gt   = (const int*)d_in[1];
    const float* aux_proj  = (const float*)d_in[2];
    const int*   aux_gt    = (const int*)d_in[3];
    const float* bank      = (const float*)d_in[4];
    float* out = (float*)d_out;

    char* ws = (char*)d_ws;
    int*   labels     = (int*)ws;                    // 524288 B (dead after k_write)
    int*   hist       = (int*)(ws + 524288);         // 40960 B
    int*   pix2row    = (int*)(ws + 565248);         // 524288 B
    int*   c_valid    = (int*)(ws + 1089536);        // 40960 B
    float* zreg       = (float*)(ws + 1130496);      // 61952 B zero region
    float* row_sumexp = zreg;
    float* S          = zreg + 10240;
    int*   pcnt       = (int*)(zreg + 15360);
    float* facc       = zreg + 15380;
    int*   done_cnt   = (int*)(zreg + 15382);
    int*   counts     = (int*)(ws + 1192448);        // 256 B (written by k_write, no pre-zero)
    float* xF         = (float*)(ws + 1192704);      // 10485760 B
    short* anchorsB   = (short*)(ws + 11678464);     // 5242880 B
    short* contrasB   = (short*)(ws + 16921344);     // 5242880 B (end 22164224)

    k_hist<<<512, 256, 0, stream>>>(main_gt, aux_gt, labels, hist, pix2row, zreg);
    k_write<<<512, 256, 0, stream>>>(labels, hist, pix2row, counts);
    k_scatter<<<32768, 256, 0, stream>>>(main_proj, aux_proj, pix2row, xF);
    k_nbc<<<AROWS / 64, 256, 0, stream>>>(xF, bank, counts, anchorsB, contrasB,
                                          c_valid, S, pcnt);
    dim3 grid(AROWS / 128, AROWS / 256);
    k_score<<<grid, 512, 0, stream>>>(anchorsB, contrasB, c_valid, row_sumexp);
    k_fin<<<AROWS / 64, 256, 0, stream>>>(anchorsB, S, counts, pcnt, row_sumexp,
                                          facc, done_cnt, out);
}

// Round 5
// 282.504 us; speedup vs baseline: 2.7464x; 2.7464x over previous
//
#include <hip/hip_runtime.h>
#include <cstdint>
#include <math.h>

#define NCLS  20
#define MSZ   512
#define DIM   256
#define HW    16384      // 128*128
#define NPIX  131072     // 4 * 2 * 16384
#define AROWS 10240      // NCLS * MSZ
#define TEMP_INV 10.0f
#define EXP2K 14.4269504088896f   // TEMP_INV * log2(e)

typedef __attribute__((ext_vector_type(8))) short bf16x8;
typedef __attribute__((ext_vector_type(4))) float f32x4;

__device__ __forceinline__ short f2bf(float f) {
    unsigned u = __float_as_uint(f);
    unsigned r = (u + 0x7FFFu + ((u >> 16) & 1u)) >> 16;
    return (short)r;
}
__device__ __forceinline__ float bf2f(short s) {
    return __uint_as_float(((unsigned)(unsigned short)s) << 16);
}
__device__ __forceinline__ float fexp2(float x) {
    float r;
    asm volatile("v_exp_f32 %0, %1" : "=v"(r) : "v"(x));
    return r;
}
// async global->LDS, 16B/lane, wave-uniform LDS base + lane*16 (global source per-lane)
__device__ __forceinline__ void gld16(const void* g, void* l) {
    __builtin_amdgcn_global_load_lds(
        (const __attribute__((address_space(1))) unsigned int*)(uintptr_t)g,
        (__attribute__((address_space(3))) unsigned int*)(unsigned int)(uintptr_t)l,
        16, 0, 0);
}

// zero-region float layout (15488 floats = 61952 B):
//   [0]       row_sumexp   (10240)
//   [10240]   S            (5120)
//   [15360]   pcnt         (20 ints)
//   [15380]   facc[2]      (loss sum, valid count)
//   [15382]   done_cnt     (int)
#define ZREG_FLOATS 15488

// ---------------- K1: labels + per-chunk class histogram + inits (no cross-block races) ----------------
__global__ __launch_bounds__(256) void k_hist(const int* __restrict__ mg,
                                              const int* __restrict__ ag,
                                              int* __restrict__ labels,
                                              int* __restrict__ hist,
                                              int* __restrict__ pix2row,
                                              float* __restrict__ zreg) {
    int chunk = blockIdx.x, t = threadIdx.x;
    int lane = t & 63;
    int gi = chunk * 256 + t;
    if (gi < ZREG_FLOATS) zreg[gi] = 0.0f;

    int n = gi;
    int b = n >> 15, r = n & 32767;
    const int* g = (r < HW) ? mg : ag;
    int p = (r < HW) ? r : (r - HW);
    int h = p >> 7, w = p & 127;
    int lab = g[(((size_t)b * 512) + (size_t)(h << 2)) * 512 + (size_t)(w << 2)];
    if (lab == 255) lab = -1;
    else if (lab == 254) lab = NCLS - 1;
    labels[n] = lab;
    pix2row[n] = -1;

    __shared__ int cnt20[NCLS];
    if (t < NCLS) cnt20[t] = 0;
    __syncthreads();
#pragma unroll
    for (int c = 0; c < NCLS; ++c) {
        unsigned long long m = __ballot(lab == c);
        if (lane == 0 && m) atomicAdd(&cnt20[c], __popcll(m));
    }
    __syncthreads();
    if (t < NCLS) hist[t * 512 + chunk] = cnt20[t];
}

// ---------------- K2: deterministic ordered compaction -> pix2row; last chunk writes counts ----------------
__global__ __launch_bounds__(256) void k_write(const int* __restrict__ labels,
                                               const int* __restrict__ hist,
                                               int* __restrict__ pix2row,
                                               int* __restrict__ counts) {
    int chunk = blockIdx.x, t = threadIdx.x;
    int lane = t & 63, wv = t >> 6;
    __shared__ int cbase[NCLS];
    __shared__ int wcnt2[4][NCLS];

#pragma unroll
    for (int cc = 0; cc < 5; ++cc) {
        int c = wv * 5 + cc;
        int s = 0;
        for (int j = lane; j < chunk; j += 64) s += hist[c * 512 + j];
#pragma unroll
        for (int o = 32; o > 0; o >>= 1) s += __shfl_down(s, o, 64);
        if (lane == 0) cbase[c] = s;
    }

    int n = chunk * 256 + t;
    int lab = labels[n];
    int myrank = 0;
#pragma unroll
    for (int c = 0; c < NCLS; ++c) {
        unsigned long long m = __ballot(lab == c);
        if (lane == 0) wcnt2[wv][c] = __popcll(m);
        if (lab == c) myrank = __popcll(m & ((1ull << lane) - 1ull));
    }
    __syncthreads();
    if (lab >= 0) {
        int base = cbase[lab] + myrank;
        for (int w = 0; w < wv; ++w) base += wcnt2[w][lab];
        if (base < MSZ) pix2row[n] = lab * MSZ + base;
    }
    // chunk 511: total count per class = prefix + own chunk (race-free, no atomics)
    if (chunk == 511 && t < NCLS)
        counts[t] = cbase[t] + wcnt2[0][t] + wcnt2[1][t] + wcnt2[2][t] + wcnt2[3][t];
}

// ---------------- K3: pix2row-first conditional read of proj, scatter selected to xF ----------------
// Only ~8% of pixels are selected; load the (L2-resident) pix2row int4 FIRST and skip the
// 16B proj load when all four lanes' rows are -1 -> HBM read traffic drops ~10x.
__global__ __launch_bounds__(256) void k_scatter(const float* __restrict__ mainp,
                                                 const float* __restrict__ auxp,
                                                 const int* __restrict__ pix2row,
                                                 float* __restrict__ xF) {
    int idx = blockIdx.x * 256 + threadIdx.x;
    int p4 = idx & 4095;
    int ch = (idx >> 12) & 255;
    int bs = idx >> 20;                          // 0..7 = b*2+src
    int b = bs >> 1, src = bs & 1;
    int4 pr = *(const int4*)(pix2row + bs * HW + p4 * 4);
    if ((pr.x & pr.y & pr.z & pr.w) < 0) return; // all four negative -> nothing selected
    const float* base = (src ? auxp : mainp) + (size_t)b * DIM * HW + (size_t)ch * HW;
    float4 v = *(const float4*)(base + p4 * 4);
    if (pr.x >= 0) xF[(size_t)pr.x * DIM + ch] = v.x;
    if (pr.y >= 0) xF[(size_t)pr.y * DIM + ch] = v.y;
    if (pr.z >= 0) xF[(size_t)pr.z * DIM + ch] = v.z;
    if (pr.w >= 0) xF[(size_t)pr.w * DIM + ch] = v.w;
}

// ---------------- K4: fused normalize + bank update + per-class S/pcnt ----------------
// block = 64 rows of one class (160 blocks); wave handles 16 rows (4 consecutive rows / iter)
__global__ __launch_bounds__(256) void k_nbc(const float* __restrict__ xF,
                                             const float* __restrict__ bank,
                                             const int* __restrict__ counts,
                                             short* __restrict__ anchorsB,
                                             short* __restrict__ contrasB,
                                             int* __restrict__ c_valid,
                                             float* __restrict__ S,
                                             int* __restrict__ pcnt) {
    int blk = blockIdx.x;
    int c = blk >> 3;
    int t = threadIdx.x, lane = t & 63, wv = t >> 6;
    int cc = counts[c];
    int base = blk * 64;
    float sacc[4] = {0.f, 0.f, 0.f, 0.f};
    int vcnt = 0;

    for (int it = 0; it < 16; ++it) {
        int a = base + it * 4 + wv;
        int m = a & 511;
        float4 xv = *(const float4*)&xF[(size_t)a * DIM + lane * 4];
        float x[4] = {xv.x, xv.y, xv.z, xv.w};
        float ss = x[0]*x[0] + x[1]*x[1] + x[2]*x[2] + x[3]*x[3];
#pragma unroll
        for (int o = 1; o < 64; o <<= 1) ss += __shfl_xor(ss, o, 64);
        float scale = 1.0f / fmaxf(sqrtf(ss), 1e-12f);
        float ax[4];
#pragma unroll
        for (int q = 0; q < 4; ++q) ax[q] = x[q] * scale;
        short4 oa;
        oa.x = f2bf(ax[0]); oa.y = f2bf(ax[1]); oa.z = f2bf(ax[2]); oa.w = f2bf(ax[3]);
        *(short4*)&anchorsB[(size_t)a * DIM + lane * 4] = oa;

        bool upd = m < cc;
        float4 bv = *(const float4*)&bank[(size_t)a * DIM + lane * 4];
        float u[4];
        u[0] = upd ? 0.999f * bv.x + 0.001f * ax[0] : bv.x;
        u[1] = upd ? 0.999f * bv.y + 0.001f * ax[1] : bv.y;
        u[2] = upd ? 0.999f * bv.z + 0.001f * ax[2] : bv.z;
        u[3] = upd ? 0.999f * bv.w + 0.001f * ax[3] : bv.w;
        float ss2 = u[0]*u[0] + u[1]*u[1] + u[2]*u[2] + u[3]*u[3];
#pragma unroll
        for (int o = 1; o < 64; o <<= 1) ss2 += __shfl_xor(ss2, o, 64);
        float nrm = sqrtf(ss2);
        float inv = 1.0f / fmaxf(nrm, 1e-12f);
        short oc[4];
        oc[0] = f2bf(upd ? u[0] * inv : bv.x);
        oc[1] = f2bf(upd ? u[1] * inv : bv.y);
        oc[2] = f2bf(upd ? u[2] * inv : bv.z);
        oc[3] = f2bf(upd ? u[3] * inv : bv.w);
        *(short4*)&contrasB[(size_t)a * DIM + lane * 4] = *(short4*)oc;
        bool valid = nrm > 0.0f;
        if (lane == 0) {
            c_valid[a] = valid ? 1 : 0;
            vcnt += valid ? 1 : 0;
        }
        if (valid) {
#pragma unroll
            for (int q = 0; q < 4; ++q) sacc[q] += bf2f(oc[q]);
        }
    }

    __shared__ float s4[4][DIM];
    __shared__ int pv[4];
#pragma unroll
    for (int q = 0; q < 4; ++q) s4[wv][lane * 4 + q] = sacc[q];
    if (lane == 0) pv[wv] = vcnt;
    __syncthreads();
    float s = s4[0][t] + s4[1][t] + s4[2][t] + s4[3][t];
    atomicAdd(&S[c * DIM + t], s);
    if (t == 0) atomicAdd(&pcnt[c], pv[0] + pv[1] + pv[2] + pv[3]);
}

// ---------------- K5: bf16 MFMA scores + fused sum-exp (v5: BK=32 dbuf, 1 barrier/tile) ----------------
// 128x256 tile, 512 threads = 8 waves (2M x 4N), wave tile 64x64, BK=32, K=256 = 8 K-tiles.
// Double-buffered LDS 2x24 KiB = 48 KiB -> still 2 blocks/CU at VGPR<=128 (launch_bounds(512,4);
// NEVER 6 - r4 showed min-waves=6 caps VGPR at 80 and spills the 64-VGPR accumulator to scratch).
// ONE barrier per K-tile: {vmcnt(0); barrier; stage(kt+1 -> buf^1); 8 ds_reads from buf;
// lgkmcnt(0); 16 MFMA}. Safe: every wave lgkm-drained its buf^1 reads in iter kt-1 before
// barrier(kt), so staging into buf^1 after barrier(kt) cannot race. After the barrier each
// wave proceeds independently (stage/read/MFMA), so MFMA of one wave overlaps ds_reads of
// another instead of lockstepping at a second barrier (r3).
// LDS layout [row][32 shorts], linear, no swizzle: each frag read's 64 lanes (16 rows x 4
// k-slots) cover one fully CONTIGUOUS 1024B region -> conflict-free by construction.
__global__ __launch_bounds__(512, 4) void k_score(const short* __restrict__ A,
                                                  const short* __restrict__ Bc,
                                                  const int* __restrict__ c_valid,
                                                  float* __restrict__ row_sumexp) {
    __shared__ short As[2][128 * 32];   // 8 KiB per buffer
    __shared__ short Bs[2][256 * 32];   // 16 KiB per buffer
    const int t = threadIdx.x;
    const int lane = t & 63, wv = t >> 6;
    const int wr = wv & 1, wc = wv >> 1;    // wave tile: rows wr*64..+64, cols wc*64..+64
    const int qr = lane >> 4, qc = lane & 15;
    const int row0 = blockIdx.x * 128, col0 = blockIdx.y * 256;

    // staging: wave-uniform LDS base + lane*16; per-lane global source.
    // lane l covers row (chunk_base + l/4), shorts (l&3)*8 .. +8 of the 32-short k-window.
    const int rsub = lane >> 2;
    const int ksub = (lane & 3) * 8;
    const short* Ag = A  + (size_t)row0 * DIM;
    const short* Bg = Bc + (size_t)col0 * DIM;

    f32x4 acc[4][4] = {};                   // [rt][ct]

    auto stage = [&](int buf, int kt) {
        // A: 128 rows -> 8 waves x 16 rows (1 gld16 each)
        gld16(Ag + (size_t)(wv * 16 + rsub) * DIM + kt * 32 + ksub,
              &As[buf][(wv * 16) * 32]);
        // B: 256 rows -> 8 waves x 32 rows (2 gld16 each)
        gld16(Bg + (size_t)(wv * 32 + rsub) * DIM + kt * 32 + ksub,
              &Bs[buf][(wv * 32) * 32]);
        gld16(Bg + (size_t)(wv * 32 + 16 + rsub) * DIM + kt * 32 + ksub,
              &Bs[buf][(wv * 32 + 16) * 32]);
    };

    stage(0, 0);
#pragma unroll
    for (int kt = 0; kt < 8; ++kt) {
        const int buf = kt & 1;
        asm volatile("s_waitcnt vmcnt(0)" ::: "memory");   // my stage(kt) landed
        asm volatile("s_barrier" ::: "memory");            // all waves' stage(kt) landed
        if (kt < 7) stage(buf ^ 1, kt + 1);                // async into idle buffer

        bf16x8 a[4], b[4];
#pragma unroll
        for (int rt = 0; rt < 4; ++rt)
            a[rt] = *(const bf16x8*)&As[buf][(wr * 64 + rt * 16 + qc) * 32 + qr * 8];
#pragma unroll
        for (int ct = 0; ct < 4; ++ct)
            b[ct] = *(const bf16x8*)&Bs[buf][(wc * 64 + ct * 16 + qc) * 32 + qr * 8];
        asm volatile("s_waitcnt lgkmcnt(0)" ::: "memory"); // my frag reads complete
        __builtin_amdgcn_sched_barrier(0);                 // (rule 18) MFMA must not hoist
#pragma unroll
        for (int rt = 0; rt < 4; ++rt)
#pragma unroll
            for (int ct = 0; ct < 4; ++ct)
                acc[rt][ct] = __builtin_amdgcn_mfma_f32_16x16x32_bf16(a[rt], b[ct], acc[rt][ct], 0, 0, 0);
    }

    // fused masked sum-exp epilogue: per row-partial over this block's 256 cols
    float cm[4];
#pragma unroll
    for (int ct = 0; ct < 4; ++ct)
        cm[ct] = c_valid[col0 + wc * 64 + ct * 16 + qc] ? 1.0f : 0.0f;
#pragma unroll
    for (int rt = 0; rt < 4; ++rt)
#pragma unroll
        for (int r = 0; r < 4; ++r) {
            float e = cm[0] * fexp2(acc[rt][0][r] * EXP2K)
                    + cm[1] * fexp2(acc[rt][1][r] * EXP2K)
                    + cm[2] * fexp2(acc[rt][2][r] * EXP2K)
                    + cm[3] * fexp2(acc[rt][3][r] * EXP2K);
#pragma unroll
            for (int o = 1; o < 16; o <<= 1) e += __shfl_xor(e, o, 64);
            if (qc == 0)
                atomicAdd(&row_sumexp[row0 + wr * 64 + rt * 16 + qr * 4 + r], e);
        }
}

// ---------------- K6: per-row loss terms + last-block final reduction ----------------
// block = 64 rows (160 blocks); pos_sum = TEMP_INV * (anchor . S[class])
__global__ __launch_bounds__(256) void k_fin(const short* __restrict__ anchorsB,
                                             const float* __restrict__ S,
                                             const int* __restrict__ counts,
                                             const int* __restrict__ pcnt,
                                             const float* __restrict__ row_sumexp,
                                             float* __restrict__ facc,
                                             int* __restrict__ done_cnt,
                                             float* __restrict__ out) {
    int blk = blockIdx.x;
    int c = blk >> 3;
    int t = threadIdx.x, lane = t & 63, wv = t >> 6;
    int pc = pcnt[c], cc = counts[c];
    float lsum = 0.0f, vc = 0.0f;

    for (int it = 0; it < 16; ++it) {
        int a = blk * 64 + it * 4 + wv;
        short4 a4 = *(const short4*)&anchorsB[(size_t)a * DIM + lane * 4];
        float4 s4 = *(const float4*)&S[c * DIM + lane * 4];
        float dot = bf2f(a4.x) * s4.x + bf2f(a4.y) * s4.y
                  + bf2f(a4.z) * s4.z + bf2f(a4.w) * s4.w;
#pragma unroll
        for (int o = 1; o < 64; o <<= 1) dot += __shfl_xor(dot, o, 64);
        if (lane == 0 && (a & 511) < cc && pc > 0) {
            float lse = logf(row_sumexp[a]);
            lsum += (TEMP_INV * dot - (float)pc * lse) / (float)pc;
            vc += 1.0f;
        }
    }

    __shared__ float wls[4], wvc[4];
    if (lane == 0) { wls[wv] = lsum; wvc[wv] = vc; }
    __syncthreads();
    if (t == 0) {
        atomicAdd(&facc[0], wls[0] + wls[1] + wls[2] + wls[3]);
        atomicAdd(&facc[1], wvc[0] + wvc[1] + wvc[2] + wvc[3]);
        __threadfence();
        unsigned d = atomicAdd((unsigned*)done_cnt, 1u);
        if (d == 159u) {   // last block: totals are globally visible via atomics
            __threadfence();
            float L = atomicAdd(&facc[0], 0.0f);
            float V = atomicAdd(&facc[1], 0.0f);
            out[0] = -L / fmaxf(V, 1.0f);
        }
    }
}

// ---------------- launch ----------------
extern "C" void kernel_launch(void* const* d_in, const int* in_sizes, int n_in,
                              void* d_out, int out_size, void* d_ws, size_t ws_size,
                              hipStream_t stream) {
    const float* main_proj = (const float*)d_in[0];
    const int*   main_gt   = (const int*)d_in[1];
    const float* aux_proj  = (const float*)d_in[2];
    const int*   aux_gt    = (const int*)d_in[3];
    const float* bank      = (const float*)d_in[4];
    float* out = (float*)d_out;

    char* ws = (char*)d_ws;
    int*   labels     = (int*)ws;                    // 524288 B (dead after k_write)
    int*   hist       = (int*)(ws + 524288);         // 40960 B
    int*   pix2row    = (int*)(ws + 565248);         // 524288 B
    int*   c_valid    = (int*)(ws + 1089536);        // 40960 B
    float* zreg       = (float*)(ws + 1130496);      // 61952 B zero region
    float* row_sumexp = zreg;
    float* S          = zreg + 10240;
    int*   pcnt       = (int*)(zreg + 15360);
    float* facc       = zreg + 15380;
    int*   done_cnt   = (int*)(zreg + 15382);
    int*   counts     = (int*)(ws + 1192448);        // 256 B (written by k_write, no pre-zero)
    float* xF         = (float*)(ws + 1192704);      // 10485760 B
    short* anchorsB   = (short*)(ws + 11678464);     // 5242880 B
    short* contrasB   = (short*)(ws + 16921344);     // 5242880 B (end 22164224)

    k_hist<<<512, 256, 0, stream>>>(main_gt, aux_gt, labels, hist, pix2row, zreg);
    k_write<<<512, 256, 0, stream>>>(labels, hist, pix2row, counts);
    k_scatter<<<32768, 256, 0, stream>>>(main_proj, aux_proj, pix2row, xF);
    k_nbc<<<AROWS / 64, 256, 0, stream>>>(xF, bank, counts, anchorsB, contrasB,
                                          c_valid, S, pcnt);
    dim3 grid(AROWS / 128, AROWS / 256);
    k_score<<<grid, 512, 0, stream>>>(anchorsB, contrasB, c_valid, row_sumexp);
    k_fin<<<AROWS / 64, 256, 0, stream>>>(anchorsB, S, counts, pcnt, row_sumexp,
                                          facc, done_cnt, out);
}

// Round 6
// 276.177 us; speedup vs baseline: 2.8093x; 1.0229x over previous
//
#include <hip/hip_runtime.h>
#include <cstdint>
#include <math.h>

#define NCLS  20
#define MSZ   512
#define DIM   256
#define HW    16384      // 128*128
#define NPIX  131072     // 4 * 2 * 16384
#define AROWS 10240      // NCLS * MSZ
#define TEMP_INV 10.0f
#define EXP2K 14.4269504088896f   // TEMP_INV * log2(e)

typedef __attribute__((ext_vector_type(8))) short bf16x8;
typedef __attribute__((ext_vector_type(4))) float f32x4;

__device__ __forceinline__ short f2bf(float f) {
    unsigned u = __float_as_uint(f);
    unsigned r = (u + 0x7FFFu + ((u >> 16) & 1u)) >> 16;
    return (short)r;
}
__device__ __forceinline__ float bf2f(short s) {
    return __uint_as_float(((unsigned)(unsigned short)s) << 16);
}
__device__ __forceinline__ float fexp2(float x) {
    float r;
    asm volatile("v_exp_f32 %0, %1" : "=v"(r) : "v"(x));
    return r;
}
// async global->LDS, 16B/lane, wave-uniform LDS base + lane*16 (global source per-lane)
__device__ __forceinline__ void gld16(const void* g, void* l) {
    __builtin_amdgcn_global_load_lds(
        (const __attribute__((address_space(1))) unsigned int*)(uintptr_t)g,
        (__attribute__((address_space(3))) unsigned int*)(unsigned int)(uintptr_t)l,
        16, 0, 0);
}

// zero-region float layout (15488 floats = 61952 B):
//   [0]       row_sumexp   (10240)
//   [10240]   S            (5120)
//   [15360]   pcnt         (20 ints)
//   [15380]   facc[2]      (loss sum, valid count)
//   [15382]   done_cnt     (int)
#define ZREG_FLOATS 15488

// ---------------- K1: labels + per-chunk class histogram + inits (no cross-block races) ----------------
__global__ __launch_bounds__(256) void k_hist(const int* __restrict__ mg,
                                              const int* __restrict__ ag,
                                              int* __restrict__ labels,
                                              int* __restrict__ hist,
                                              int* __restrict__ pix2row,
                                              float* __restrict__ zreg) {
    int chunk = blockIdx.x, t = threadIdx.x;
    int lane = t & 63;
    int gi = chunk * 256 + t;
    if (gi < ZREG_FLOATS) zreg[gi] = 0.0f;

    int n = gi;
    int b = n >> 15, r = n & 32767;
    const int* g = (r < HW) ? mg : ag;
    int p = (r < HW) ? r : (r - HW);
    int h = p >> 7, w = p & 127;
    int lab = g[(((size_t)b * 512) + (size_t)(h << 2)) * 512 + (size_t)(w << 2)];
    if (lab == 255) lab = -1;
    else if (lab == 254) lab = NCLS - 1;
    labels[n] = lab;
    pix2row[n] = -1;

    __shared__ int cnt20[NCLS];
    if (t < NCLS) cnt20[t] = 0;
    __syncthreads();
#pragma unroll
    for (int c = 0; c < NCLS; ++c) {
        unsigned long long m = __ballot(lab == c);
        if (lane == 0 && m) atomicAdd(&cnt20[c], __popcll(m));
    }
    __syncthreads();
    if (t < NCLS) hist[t * 512 + chunk] = cnt20[t];
}

// ---------------- K2: deterministic ordered compaction -> pix2row; last chunk writes counts ----------------
__global__ __launch_bounds__(256) void k_write(const int* __restrict__ labels,
                                               const int* __restrict__ hist,
                                               int* __restrict__ pix2row,
                                               int* __restrict__ counts) {
    int chunk = blockIdx.x, t = threadIdx.x;
    int lane = t & 63, wv = t >> 6;
    __shared__ int cbase[NCLS];
    __shared__ int wcnt2[4][NCLS];

#pragma unroll
    for (int cc = 0; cc < 5; ++cc) {
        int c = wv * 5 + cc;
        int s = 0;
        for (int j = lane; j < chunk; j += 64) s += hist[c * 512 + j];
#pragma unroll
        for (int o = 32; o > 0; o >>= 1) s += __shfl_down(s, o, 64);
        if (lane == 0) cbase[c] = s;
    }

    int n = chunk * 256 + t;
    int lab = labels[n];
    int myrank = 0;
#pragma unroll
    for (int c = 0; c < NCLS; ++c) {
        unsigned long long m = __ballot(lab == c);
        if (lane == 0) wcnt2[wv][c] = __popcll(m);
        if (lab == c) myrank = __popcll(m & ((1ull << lane) - 1ull));
    }
    __syncthreads();
    if (lab >= 0) {
        int base = cbase[lab] + myrank;
        for (int w = 0; w < wv; ++w) base += wcnt2[w][lab];
        if (base < MSZ) pix2row[n] = lab * MSZ + base;
    }
    // chunk 511: total count per class = prefix + own chunk (race-free, no atomics)
    if (chunk == 511 && t < NCLS)
        counts[t] = cbase[t] + wcnt2[0][t] + wcnt2[1][t] + wcnt2[2][t] + wcnt2[3][t];
}

// ---------------- K3: pix2row-first conditional read of proj, scatter selected to xF ----------------
// Only ~8% of pixels are selected; load the (L2-resident) pix2row int4 FIRST and skip the
// 16B proj load when all four lanes' rows are -1 -> HBM read traffic drops ~10x.
// (r5 measured: non-score time 219.8 -> 193.3 us with this skip. Keep.)
__global__ __launch_bounds__(256) void k_scatter(const float* __restrict__ mainp,
                                                 const float* __restrict__ auxp,
                                                 const int* __restrict__ pix2row,
                                                 float* __restrict__ xF) {
    int idx = blockIdx.x * 256 + threadIdx.x;
    int p4 = idx & 4095;
    int ch = (idx >> 12) & 255;
    int bs = idx >> 20;                          // 0..7 = b*2+src
    int b = bs >> 1, src = bs & 1;
    int4 pr = *(const int4*)(pix2row + bs * HW + p4 * 4);
    if ((pr.x & pr.y & pr.z & pr.w) < 0) return; // all four negative -> nothing selected
    const float* base = (src ? auxp : mainp) + (size_t)b * DIM * HW + (size_t)ch * HW;
    float4 v = *(const float4*)(base + p4 * 4);
    if (pr.x >= 0) xF[(size_t)pr.x * DIM + ch] = v.x;
    if (pr.y >= 0) xF[(size_t)pr.y * DIM + ch] = v.y;
    if (pr.z >= 0) xF[(size_t)pr.z * DIM + ch] = v.z;
    if (pr.w >= 0) xF[(size_t)pr.w * DIM + ch] = v.w;
}

// ---------------- K4: fused normalize + bank update + per-class S/pcnt (v2: 640 blocks) ----------------
// r5 analysis: 160 blocks = 0.625 blocks/CU left 37% of CUs idle on a latency-bound kernel
// (two dependent 6-step shuffle reductions + HBM-latency loads per row). Same algorithm,
// 16 rows/block -> 640 blocks (2.5 blocks/CU), 4 iterations. Atomics: 32 blocks/class on
// S[c][256] + pcnt[c] - trivial contention.
__global__ __launch_bounds__(256) void k_nbc(const float* __restrict__ xF,
                                             const float* __restrict__ bank,
                                             const int* __restrict__ counts,
                                             short* __restrict__ anchorsB,
                                             short* __restrict__ contrasB,
                                             int* __restrict__ c_valid,
                                             float* __restrict__ S,
                                             int* __restrict__ pcnt) {
    int blk = blockIdx.x;
    int c = blk >> 5;                  // 32 blocks per class
    int t = threadIdx.x, lane = t & 63, wv = t >> 6;
    int cc = counts[c];
    int base = blk * 16;
    float sacc[4] = {0.f, 0.f, 0.f, 0.f};
    int vcnt = 0;

    for (int it = 0; it < 4; ++it) {
        int a = base + it * 4 + wv;
        int m = a & 511;
        float4 xv = *(const float4*)&xF[(size_t)a * DIM + lane * 4];
        float x[4] = {xv.x, xv.y, xv.z, xv.w};
        float ss = x[0]*x[0] + x[1]*x[1] + x[2]*x[2] + x[3]*x[3];
#pragma unroll
        for (int o = 1; o < 64; o <<= 1) ss += __shfl_xor(ss, o, 64);
        float scale = 1.0f / fmaxf(sqrtf(ss), 1e-12f);
        float ax[4];
#pragma unroll
        for (int q = 0; q < 4; ++q) ax[q] = x[q] * scale;
        short4 oa;
        oa.x = f2bf(ax[0]); oa.y = f2bf(ax[1]); oa.z = f2bf(ax[2]); oa.w = f2bf(ax[3]);
        *(short4*)&anchorsB[(size_t)a * DIM + lane * 4] = oa;

        bool upd = m < cc;
        float4 bv = *(const float4*)&bank[(size_t)a * DIM + lane * 4];
        float u[4];
        u[0] = upd ? 0.999f * bv.x + 0.001f * ax[0] : bv.x;
        u[1] = upd ? 0.999f * bv.y + 0.001f * ax[1] : bv.y;
        u[2] = upd ? 0.999f * bv.z + 0.001f * ax[2] : bv.z;
        u[3] = upd ? 0.999f * bv.w + 0.001f * ax[3] : bv.w;
        float ss2 = u[0]*u[0] + u[1]*u[1] + u[2]*u[2] + u[3]*u[3];
#pragma unroll
        for (int o = 1; o < 64; o <<= 1) ss2 += __shfl_xor(ss2, o, 64);
        float nrm = sqrtf(ss2);
        float inv = 1.0f / fmaxf(nrm, 1e-12f);
        short oc[4];
        oc[0] = f2bf(upd ? u[0] * inv : bv.x);
        oc[1] = f2bf(upd ? u[1] * inv : bv.y);
        oc[2] = f2bf(upd ? u[2] * inv : bv.z);
        oc[3] = f2bf(upd ? u[3] * inv : bv.w);
        *(short4*)&contrasB[(size_t)a * DIM + lane * 4] = *(short4*)oc;
        bool valid = nrm > 0.0f;
        if (lane == 0) {
            c_valid[a] = valid ? 1 : 0;
            vcnt += valid ? 1 : 0;
        }
        if (valid) {
#pragma unroll
            for (int q = 0; q < 4; ++q) sacc[q] += bf2f(oc[q]);
        }
    }

    __shared__ float s4[4][DIM];
    __shared__ int pv[4];
#pragma unroll
    for (int q = 0; q < 4; ++q) s4[wv][lane * 4 + q] = sacc[q];
    if (lane == 0) pv[wv] = vcnt;
    __syncthreads();
    float s = s4[0][t] + s4[1][t] + s4[2][t] + s4[3][t];
    atomicAdd(&S[c * DIM + t], s);
    if (t == 0) atomicAdd(&pcnt[c], pv[0] + pv[1] + pv[2] + pv[3]);
}

// ---------------- K5: bf16 MFMA scores + fused sum-exp (r3 config: best measured, restored) ----------------
// 128x256 tile, 512 threads = 8 waves (2M x 4N), wave tile 64x64, BK=64, K=256 = 4 K-tiles.
// SINGLE-buffer LDS (48 KiB) -> 2 blocks/CU at VGPR=64 via __launch_bounds__(512,4).
// Full XOR swizzle: 128B rows, slot=((kk*4+qr)^(qc&7)) - the ONLY measured-zero-conflict
// layout (r1/r2/r3 = 0; 64B-row variants r0/r5 = 6.55M). 2 barriers/K-tile.
// Measured: 78 us, MfmaUtil 28%, 0 conflicts. Do not churn further (r1/r2/r4/r5 all worse).
__global__ __launch_bounds__(512, 4) void k_score(const short* __restrict__ A,
                                                  const short* __restrict__ Bc,
                                                  const int* __restrict__ c_valid,
                                                  float* __restrict__ row_sumexp) {
    __shared__ short As[128 * 64];   // 16 KiB
    __shared__ short Bs[256 * 64];   // 32 KiB
    const int t = threadIdx.x;
    const int lane = t & 63, wv = t >> 6;
    const int wr = wv & 1, wc = wv >> 1;    // wave tile: rows wr*64..+64, cols wc*64..+64
    const int qr = lane >> 4, qc = lane & 15;
    const int s7 = qc & 7;
    const int row0 = blockIdx.x * 128, col0 = blockIdx.y * 256;

    // staging: thread t covers row rl8 = t>>3 of each 64-row chunk, linear slot t&7.
    // source fetches data slot sdat = (t&7)^(row&7) so LDS(row, slot) holds data slot^(row&7).
    const int rl8 = t >> 3;
    const int sdat = (t & 7) ^ (rl8 & 7);
    const short* Ag = A  + (size_t)row0 * DIM;
    const short* Bg = Bc + (size_t)col0 * DIM;

    // frag-read slot offsets (shorts): data slot kk*4+qr lives at ((kk*4+qr)^(row&7)),
    // row&7 == qc&7 for all fragment rows (row = mult8 + qc).
    const int sl0 = ((0 + qr) ^ s7) * 8;
    const int sl1 = ((4 + qr) ^ s7) * 8;

    f32x4 acc[4][4] = {};                   // [rt][ct]

    auto stage = [&](int kt) {
#pragma unroll
        for (int r = 0; r < 2; ++r)
            gld16(Ag + (size_t)(r * 64 + rl8) * DIM + kt * 64 + sdat * 8,
                  &As[(r * 64 + wv * 8) * 64]);
#pragma unroll
        for (int r = 0; r < 4; ++r)
            gld16(Bg + (size_t)(r * 64 + rl8) * DIM + kt * 64 + sdat * 8,
                  &Bs[(r * 64 + wv * 8) * 64]);
    };

    stage(0);
    for (int kt = 0; kt < 4; ++kt) {
        asm volatile("s_waitcnt vmcnt(0)" ::: "memory");   // stage(kt) landed (issued 1 tile ago)
        asm volatile("s_barrier" ::: "memory");            // buffer ready for all waves

        bf16x8 a0[4], b0[4], a1[4], b1[4];
#pragma unroll
        for (int rt = 0; rt < 4; ++rt)
            a0[rt] = *(const bf16x8*)&As[(wr * 64 + rt * 16 + qc) * 64 + sl0];
#pragma unroll
        for (int ct = 0; ct < 4; ++ct)
            b0[ct] = *(const bf16x8*)&Bs[(wc * 64 + ct * 16 + qc) * 64 + sl0];
#pragma unroll
        for (int rt = 0; rt < 4; ++rt)
#pragma unroll
            for (int ct = 0; ct < 4; ++ct)
                acc[rt][ct] = __builtin_amdgcn_mfma_f32_16x16x32_bf16(a0[rt], b0[ct], acc[rt][ct], 0, 0, 0);
#pragma unroll
        for (int rt = 0; rt < 4; ++rt)
            a1[rt] = *(const bf16x8*)&As[(wr * 64 + rt * 16 + qc) * 64 + sl1];
#pragma unroll
        for (int ct = 0; ct < 4; ++ct)
            b1[ct] = *(const bf16x8*)&Bs[(wc * 64 + ct * 16 + qc) * 64 + sl1];

        asm volatile("s_waitcnt lgkmcnt(0)" ::: "memory"); // all my ds_reads complete
        __builtin_amdgcn_sched_barrier(0);                 // (rule 18) nothing hoists above
        asm volatile("s_barrier" ::: "memory");            // all waves done reading buffer
        if (kt < 3) stage(kt + 1);                         // async overwrite, lands during MFMA+next wait

#pragma unroll
        for (int rt = 0; rt < 4; ++rt)
#pragma unroll
            for (int ct = 0; ct < 4; ++ct)
                acc[rt][ct] = __builtin_amdgcn_mfma_f32_16x16x32_bf16(a1[rt], b1[ct], acc[rt][ct], 0, 0, 0);
    }

    // fused masked sum-exp epilogue: per row-partial over this block's 256 cols
    float cm[4];
#pragma unroll
    for (int ct = 0; ct < 4; ++ct)
        cm[ct] = c_valid[col0 + wc * 64 + ct * 16 + qc] ? 1.0f : 0.0f;
#pragma unroll
    for (int rt = 0; rt < 4; ++rt)
#pragma unroll
        for (int r = 0; r < 4; ++r) {
            float e = cm[0] * fexp2(acc[rt][0][r] * EXP2K)
                    + cm[1] * fexp2(acc[rt][1][r] * EXP2K)
                    + cm[2] * fexp2(acc[rt][2][r] * EXP2K)
                    + cm[3] * fexp2(acc[rt][3][r] * EXP2K);
#pragma unroll
            for (int o = 1; o < 16; o <<= 1) e += __shfl_xor(e, o, 64);
            if (qc == 0)
                atomicAdd(&row_sumexp[row0 + wr * 64 + rt * 16 + qr * 4 + r], e);
        }
}

// ---------------- K6: per-row loss terms + last-block final reduction (v2: 640 blocks) ----------------
// Same occupancy fix as k_nbc: 16 rows/block -> 640 blocks; done threshold 639.
__global__ __launch_bounds__(256) void k_fin(const short* __restrict__ anchorsB,
                                             const float* __restrict__ S,
                                             const int* __restrict__ counts,
                                             const int* __restrict__ pcnt,
                                             const float* __restrict__ row_sumexp,
                                             float* __restrict__ facc,
                                             int* __restrict__ done_cnt,
                                             float* __restrict__ out) {
    int blk = blockIdx.x;
    int c = blk >> 5;                  // 32 blocks per class
    int t = threadIdx.x, lane = t & 63, wv = t >> 6;
    int pc = pcnt[c], cc = counts[c];
    float lsum = 0.0f, vc = 0.0f;

    for (int it = 0; it < 4; ++it) {
        int a = blk * 16 + it * 4 + wv;
        short4 a4 = *(const short4*)&anchorsB[(size_t)a * DIM + lane * 4];
        float4 s4 = *(const float4*)&S[c * DIM + lane * 4];
        float dot = bf2f(a4.x) * s4.x + bf2f(a4.y) * s4.y
                  + bf2f(a4.z) * s4.z + bf2f(a4.w) * s4.w;
#pragma unroll
        for (int o = 1; o < 64; o <<= 1) dot += __shfl_xor(dot, o, 64);
        if (lane == 0 && (a & 511) < cc && pc > 0) {
            float lse = logf(row_sumexp[a]);
            lsum += (TEMP_INV * dot - (float)pc * lse) / (float)pc;
            vc += 1.0f;
        }
    }

    __shared__ float wls[4], wvc[4];
    if (lane == 0) { wls[wv] = lsum; wvc[wv] = vc; }
    __syncthreads();
    if (t == 0) {
        atomicAdd(&facc[0], wls[0] + wls[1] + wls[2] + wls[3]);
        atomicAdd(&facc[1], wvc[0] + wvc[1] + wvc[2] + wvc[3]);
        __threadfence();
        unsigned d = atomicAdd((unsigned*)done_cnt, 1u);
        if (d == 639u) {   // last block: totals are globally visible via atomics
            __threadfence();
            float L = atomicAdd(&facc[0], 0.0f);
            float V = atomicAdd(&facc[1], 0.0f);
            out[0] = -L / fmaxf(V, 1.0f);
        }
    }
}

// ---------------- launch ----------------
extern "C" void kernel_launch(void* const* d_in, const int* in_sizes, int n_in,
                              void* d_out, int out_size, void* d_ws, size_t ws_size,
                              hipStream_t stream) {
    const float* main_proj = (const float*)d_in[0];
    const int*   main_gt   = (const int*)d_in[1];
    const float* aux_proj  = (const float*)d_in[2];
    const int*   aux_gt    = (const int*)d_in[3];
    const float* bank      = (const float*)d_in[4];
    float* out = (float*)d_out;

    char* ws = (char*)d_ws;
    int*   labels     = (int*)ws;                    // 524288 B (dead after k_write)
    int*   hist       = (int*)(ws + 524288);         // 40960 B
    int*   pix2row    = (int*)(ws + 565248);         // 524288 B
    int*   c_valid    = (int*)(ws + 1089536);        // 40960 B
    float* zreg       = (float*)(ws + 1130496);      // 61952 B zero region
    float* row_sumexp = zreg;
    float* S          = zreg + 10240;
    int*   pcnt       = (int*)(zreg + 15360);
    float* facc       = zreg + 15380;
    int*   done_cnt   = (int*)(zreg + 15382);
    int*   counts     = (int*)(ws + 1192448);        // 256 B (written by k_write, no pre-zero)
    float* xF         = (float*)(ws + 1192704);      // 10485760 B
    short* anchorsB   = (short*)(ws + 11678464);     // 5242880 B
    short* contrasB   = (short*)(ws + 16921344);     // 5242880 B (end 22164224)

    k_hist<<<512, 256, 0, stream>>>(main_gt, aux_gt, labels, hist, pix2row, zreg);
    k_write<<<512, 256, 0, stream>>>(labels, hist, pix2row, counts);
    k_scatter<<<32768, 256, 0, stream>>>(main_proj, aux_proj, pix2row, xF);
    k_nbc<<<AROWS / 16, 256, 0, stream>>>(xF, bank, counts, anchorsB, contrasB,
                                          c_valid, S, pcnt);
    dim3 grid(AROWS / 128, AROWS / 256);
    k_score<<<grid, 512, 0, stream>>>(anchorsB, contrasB, c_valid, row_sumexp);
    k_fin<<<AROWS / 16, 256, 0, stream>>>(anchorsB, S, counts, pcnt, row_sumexp,
                                          facc, done_cnt, out);
}

// Round 7
// 260.077 us; speedup vs baseline: 2.9832x; 1.0619x over previous
//
#include <hip/hip_runtime.h>
#include <cstdint>
#include <math.h>

#define NCLS  20
#define MSZ   512
#define DIM   256
#define HW    16384      // 128*128
#define NPIX  131072     // 4 * 2 * 16384
#define AROWS 10240      // NCLS * MSZ
#define TEMP_INV 10.0f
#define EXP2K 14.4269504088896f   // TEMP_INV * log2(e)

typedef __attribute__((ext_vector_type(8))) short bf16x8;
typedef __attribute__((ext_vector_type(4))) float f32x4;

__device__ __forceinline__ short f2bf(float f) {
    unsigned u = __float_as_uint(f);
    unsigned r = (u + 0x7FFFu + ((u >> 16) & 1u)) >> 16;
    return (short)r;
}
__device__ __forceinline__ float bf2f(short s) {
    return __uint_as_float(((unsigned)(unsigned short)s) << 16);
}
__device__ __forceinline__ float fexp2(float x) {
    float r;
    asm volatile("v_exp_f32 %0, %1" : "=v"(r) : "v"(x));
    return r;
}
// async global->LDS, 16B/lane, wave-uniform LDS base + lane*16 (global source per-lane)
__device__ __forceinline__ void gld16(const void* g, void* l) {
    __builtin_amdgcn_global_load_lds(
        (const __attribute__((address_space(1))) unsigned int*)(uintptr_t)g,
        (__attribute__((address_space(3))) unsigned int*)(unsigned int)(uintptr_t)l,
        16, 0, 0);
}

// zero-region float layout (15488 floats = 61952 B):
//   [0]       row_sumexp   (10240)
//   [10240]   S            (5120)
//   [15360]   pcnt         (20 ints)
//   [15380]   facc[2]      (loss sum, valid count)
//   [15382]   done_cnt     (int)
#define ZREG_FLOATS 15488

// ---------------- K1: labels + per-chunk class histogram + inits (no cross-block races) ----------------
__global__ __launch_bounds__(256) void k_hist(const int* __restrict__ mg,
                                              const int* __restrict__ ag,
                                              int* __restrict__ labels,
                                              int* __restrict__ hist,
                                              int* __restrict__ row2pix,
                                              float* __restrict__ zreg) {
    int chunk = blockIdx.x, t = threadIdx.x;
    int lane = t & 63;
    int gi = chunk * 256 + t;
    if (gi < ZREG_FLOATS) zreg[gi] = 0.0f;
    if (gi < AROWS) row2pix[gi] = -1;

    int n = gi;
    int b = n >> 15, r = n & 32767;
    const int* g = (r < HW) ? mg : ag;
    int p = (r < HW) ? r : (r - HW);
    int h = p >> 7, w = p & 127;
    int lab = g[(((size_t)b * 512) + (size_t)(h << 2)) * 512 + (size_t)(w << 2)];
    if (lab == 255) lab = -1;
    else if (lab == 254) lab = NCLS - 1;
    labels[n] = lab;

    __shared__ int cnt20[NCLS];
    if (t < NCLS) cnt20[t] = 0;
    __syncthreads();
#pragma unroll
    for (int c = 0; c < NCLS; ++c) {
        unsigned long long m = __ballot(lab == c);
        if (lane == 0 && m) atomicAdd(&cnt20[c], __popcll(m));
    }
    __syncthreads();
    if (t < NCLS) hist[t * 512 + chunk] = cnt20[t];
}

// ---------------- K2: deterministic ordered compaction -> row2pix; last chunk writes counts ----------------
// Emits the INVERSE map (row -> source pixel index), consumed by k_nbc's direct gather.
__global__ __launch_bounds__(256) void k_write(const int* __restrict__ labels,
                                               const int* __restrict__ hist,
                                               int* __restrict__ row2pix,
                                               int* __restrict__ counts) {
    int chunk = blockIdx.x, t = threadIdx.x;
    int lane = t & 63, wv = t >> 6;
    __shared__ int cbase[NCLS];
    __shared__ int wcnt2[4][NCLS];

#pragma unroll
    for (int cc = 0; cc < 5; ++cc) {
        int c = wv * 5 + cc;
        int s = 0;
        for (int j = lane; j < chunk; j += 64) s += hist[c * 512 + j];
#pragma unroll
        for (int o = 32; o > 0; o >>= 1) s += __shfl_down(s, o, 64);
        if (lane == 0) cbase[c] = s;
    }

    int n = chunk * 256 + t;
    int lab = labels[n];
    int myrank = 0;
#pragma unroll
    for (int c = 0; c < NCLS; ++c) {
        unsigned long long m = __ballot(lab == c);
        if (lane == 0) wcnt2[wv][c] = __popcll(m);
        if (lab == c) myrank = __popcll(m & ((1ull << lane) - 1ull));
    }
    __syncthreads();
    if (lab >= 0) {
        int base = cbase[lab] + myrank;
        for (int w = 0; w < wv; ++w) base += wcnt2[w][lab];
        if (base < MSZ) row2pix[lab * MSZ + base] = n;
    }
    // chunk 511: total count per class = prefix + own chunk (race-free, no atomics)
    if (chunk == 511 && t < NCLS)
        counts[t] = cbase[t] + wcnt2[0][t] + wcnt2[1][t] + wcnt2[2][t] + wcnt2[3][t];
}

// ---------------- K4: fused gather + normalize + bank update + per-class S/pcnt ----------------
// v3: k_scatter + xF round-trip DELETED. Each row gathers its 256 channels directly from
// proj via row2pix (4 independent 4B gathers/lane at stride HW; wave-uniform row, no
// divergence). 640 blocks (16 rows each) for gather-latency hiding; full it-unroll so all
// 16 gathers issue before the dependent shuffle chains.
__global__ __launch_bounds__(256) void k_nbc(const float* __restrict__ mainp,
                                             const float* __restrict__ auxp,
                                             const int* __restrict__ row2pix,
                                             const float* __restrict__ bank,
                                             const int* __restrict__ counts,
                                             short* __restrict__ anchorsB,
                                             short* __restrict__ contrasB,
                                             int* __restrict__ c_valid,
                                             float* __restrict__ S,
                                             int* __restrict__ pcnt) {
    int blk = blockIdx.x;
    int c = blk >> 5;                  // 32 blocks per class
    int t = threadIdx.x, lane = t & 63, wv = t >> 6;
    int cc = counts[c];
    int base = blk * 16;
    float sacc[4] = {0.f, 0.f, 0.f, 0.f};
    int vcnt = 0;

#pragma unroll
    for (int it = 0; it < 4; ++it) {
        int a = base + it * 4 + wv;
        int m = a & 511;
        int n = row2pix[a];            // wave-uniform broadcast load
        float x[4];
        if (n >= 0) {
            int b = n >> 15, r = n & 32767;
            const float* src = (r < HW) ? mainp : auxp;
            int p = (r < HW) ? r : (r - HW);
            const float* gp = src + (size_t)b * DIM * HW + p;
#pragma unroll
            for (int q = 0; q < 4; ++q)
                x[q] = gp[(size_t)(lane * 4 + q) * HW];
        } else {
            x[0] = x[1] = x[2] = x[3] = 0.0f;   // unreachable when counts >= MSZ; masked downstream
        }
        float ss = x[0]*x[0] + x[1]*x[1] + x[2]*x[2] + x[3]*x[3];
#pragma unroll
        for (int o = 1; o < 64; o <<= 1) ss += __shfl_xor(ss, o, 64);
        float scale = 1.0f / fmaxf(sqrtf(ss), 1e-12f);
        float ax[4];
#pragma unroll
        for (int q = 0; q < 4; ++q) ax[q] = x[q] * scale;
        short4 oa;
        oa.x = f2bf(ax[0]); oa.y = f2bf(ax[1]); oa.z = f2bf(ax[2]); oa.w = f2bf(ax[3]);
        *(short4*)&anchorsB[(size_t)a * DIM + lane * 4] = oa;

        bool upd = m < cc;
        float4 bv = *(const float4*)&bank[(size_t)a * DIM + lane * 4];
        float u[4];
        u[0] = upd ? 0.999f * bv.x + 0.001f * ax[0] : bv.x;
        u[1] = upd ? 0.999f * bv.y + 0.001f * ax[1] : bv.y;
        u[2] = upd ? 0.999f * bv.z + 0.001f * ax[2] : bv.z;
        u[3] = upd ? 0.999f * bv.w + 0.001f * ax[3] : bv.w;
        float ss2 = u[0]*u[0] + u[1]*u[1] + u[2]*u[2] + u[3]*u[3];
#pragma unroll
        for (int o = 1; o < 64; o <<= 1) ss2 += __shfl_xor(ss2, o, 64);
        float nrm = sqrtf(ss2);
        float inv = 1.0f / fmaxf(nrm, 1e-12f);
        short oc[4];
        oc[0] = f2bf(upd ? u[0] * inv : bv.x);
        oc[1] = f2bf(upd ? u[1] * inv : bv.y);
        oc[2] = f2bf(upd ? u[2] * inv : bv.z);
        oc[3] = f2bf(upd ? u[3] * inv : bv.w);
        *(short4*)&contrasB[(size_t)a * DIM + lane * 4] = *(short4*)oc;
        bool valid = nrm > 0.0f;
        if (lane == 0) {
            c_valid[a] = valid ? 1 : 0;
            vcnt += valid ? 1 : 0;
        }
        if (valid) {
#pragma unroll
            for (int q = 0; q < 4; ++q) sacc[q] += bf2f(oc[q]);
        }
    }

    __shared__ float s4[4][DIM];
    __shared__ int pv[4];
#pragma unroll
    for (int q = 0; q < 4; ++q) s4[wv][lane * 4 + q] = sacc[q];
    if (lane == 0) pv[wv] = vcnt;
    __syncthreads();
    float s = s4[0][t] + s4[1][t] + s4[2][t] + s4[3][t];
    atomicAdd(&S[c * DIM + t], s);
    if (t == 0) atomicAdd(&pcnt[c], pv[0] + pv[1] + pv[2] + pv[3]);
}

// ---------------- K5: bf16 MFMA scores + fused sum-exp (r3/r6 config: best measured, FROZEN) ----------------
// 128x256 tile, 512 threads = 8 waves (2M x 4N), wave tile 64x64, BK=64, K=256 = 4 K-tiles.
// SINGLE-buffer LDS (48 KiB) -> 2 blocks/CU at VGPR=64 via __launch_bounds__(512,4).
// Full XOR swizzle: 128B rows, slot=((kk*4+qr)^(qc&7)) - the ONLY measured-zero-conflict
// layout (r1/r2/r3/r6 = 0; 64B-row variants r0/r5 = 6.55M). 2 barriers/K-tile.
// Measured: 76 us, MfmaUtil 28.8%, 0 conflicts = 705 TF, at the 2-phase structural ceiling.
// K=256 (4 K-tiles) gives no steady state for deeper pipelines (r1/r2: -35%). FROZEN.
__global__ __launch_bounds__(512, 4) void k_score(const short* __restrict__ A,
                                                  const short* __restrict__ Bc,
                                                  const int* __restrict__ c_valid,
                                                  float* __restrict__ row_sumexp) {
    __shared__ short As[128 * 64];   // 16 KiB
    __shared__ short Bs[256 * 64];   // 32 KiB
    const int t = threadIdx.x;
    const int lane = t & 63, wv = t >> 6;
    const int wr = wv & 1, wc = wv >> 1;    // wave tile: rows wr*64..+64, cols wc*64..+64
    const int qr = lane >> 4, qc = lane & 15;
    const int s7 = qc & 7;
    const int row0 = blockIdx.x * 128, col0 = blockIdx.y * 256;

    // staging: thread t covers row rl8 = t>>3 of each 64-row chunk, linear slot t&7.
    // source fetches data slot sdat = (t&7)^(row&7) so LDS(row, slot) holds data slot^(row&7).
    const int rl8 = t >> 3;
    const int sdat = (t & 7) ^ (rl8 & 7);
    const short* Ag = A  + (size_t)row0 * DIM;
    const short* Bg = Bc + (size_t)col0 * DIM;

    // frag-read slot offsets (shorts): data slot kk*4+qr lives at ((kk*4+qr)^(row&7)),
    // row&7 == qc&7 for all fragment rows (row = mult8 + qc).
    const int sl0 = ((0 + qr) ^ s7) * 8;
    const int sl1 = ((4 + qr) ^ s7) * 8;

    f32x4 acc[4][4] = {};                   // [rt][ct]

    auto stage = [&](int kt) {
#pragma unroll
        for (int r = 0; r < 2; ++r)
            gld16(Ag + (size_t)(r * 64 + rl8) * DIM + kt * 64 + sdat * 8,
                  &As[(r * 64 + wv * 8) * 64]);
#pragma unroll
        for (int r = 0; r < 4; ++r)
            gld16(Bg + (size_t)(r * 64 + rl8) * DIM + kt * 64 + sdat * 8,
                  &Bs[(r * 64 + wv * 8) * 64]);
    };

    stage(0);
    for (int kt = 0; kt < 4; ++kt) {
        asm volatile("s_waitcnt vmcnt(0)" ::: "memory");   // stage(kt) landed (issued 1 tile ago)
        asm volatile("s_barrier" ::: "memory");            // buffer ready for all waves

        bf16x8 a0[4], b0[4], a1[4], b1[4];
#pragma unroll
        for (int rt = 0; rt < 4; ++rt)
            a0[rt] = *(const bf16x8*)&As[(wr * 64 + rt * 16 + qc) * 64 + sl0];
#pragma unroll
        for (int ct = 0; ct < 4; ++ct)
            b0[ct] = *(const bf16x8*)&Bs[(wc * 64 + ct * 16 + qc) * 64 + sl0];
#pragma unroll
        for (int rt = 0; rt < 4; ++rt)
#pragma unroll
            for (int ct = 0; ct < 4; ++ct)
                acc[rt][ct] = __builtin_amdgcn_mfma_f32_16x16x32_bf16(a0[rt], b0[ct], acc[rt][ct], 0, 0, 0);
#pragma unroll
        for (int rt = 0; rt < 4; ++rt)
            a1[rt] = *(const bf16x8*)&As[(wr * 64 + rt * 16 + qc) * 64 + sl1];
#pragma unroll
        for (int ct = 0; ct < 4; ++ct)
            b1[ct] = *(const bf16x8*)&Bs[(wc * 64 + ct * 16 + qc) * 64 + sl1];

        asm volatile("s_waitcnt lgkmcnt(0)" ::: "memory"); // all my ds_reads complete
        __builtin_amdgcn_sched_barrier(0);                 // (rule 18) nothing hoists above
        asm volatile("s_barrier" ::: "memory");            // all waves done reading buffer
        if (kt < 3) stage(kt + 1);                         // async overwrite, lands during MFMA+next wait

#pragma unroll
        for (int rt = 0; rt < 4; ++rt)
#pragma unroll
            for (int ct = 0; ct < 4; ++ct)
                acc[rt][ct] = __builtin_amdgcn_mfma_f32_16x16x32_bf16(a1[rt], b1[ct], acc[rt][ct], 0, 0, 0);
    }

    // fused masked sum-exp epilogue: per row-partial over this block's 256 cols
    float cm[4];
#pragma unroll
    for (int ct = 0; ct < 4; ++ct)
        cm[ct] = c_valid[col0 + wc * 64 + ct * 16 + qc] ? 1.0f : 0.0f;
#pragma unroll
    for (int rt = 0; rt < 4; ++rt)
#pragma unroll
        for (int r = 0; r < 4; ++r) {
            float e = cm[0] * fexp2(acc[rt][0][r] * EXP2K)
                    + cm[1] * fexp2(acc[rt][1][r] * EXP2K)
                    + cm[2] * fexp2(acc[rt][2][r] * EXP2K)
                    + cm[3] * fexp2(acc[rt][3][r] * EXP2K);
#pragma unroll
            for (int o = 1; o < 16; o <<= 1) e += __shfl_xor(e, o, 64);
            if (qc == 0)
                atomicAdd(&row_sumexp[row0 + wr * 64 + rt * 16 + qr * 4 + r], e);
        }
}

// ---------------- K6: per-row loss terms + last-block final reduction (640 blocks) ----------------
__global__ __launch_bounds__(256) void k_fin(const short* __restrict__ anchorsB,
                                             const float* __restrict__ S,
                                             const int* __restrict__ counts,
                                             const int* __restrict__ pcnt,
                                             const float* __restrict__ row_sumexp,
                                             float* __restrict__ facc,
                                             int* __restrict__ done_cnt,
                                             float* __restrict__ out) {
    int blk = blockIdx.x;
    int c = blk >> 5;                  // 32 blocks per class
    int t = threadIdx.x, lane = t & 63, wv = t >> 6;
    int pc = pcnt[c], cc = counts[c];
    float lsum = 0.0f, vc = 0.0f;

    for (int it = 0; it < 4; ++it) {
        int a = blk * 16 + it * 4 + wv;
        short4 a4 = *(const short4*)&anchorsB[(size_t)a * DIM + lane * 4];
        float4 s4 = *(const float4*)&S[c * DIM + lane * 4];
        float dot = bf2f(a4.x) * s4.x + bf2f(a4.y) * s4.y
                  + bf2f(a4.z) * s4.z + bf2f(a4.w) * s4.w;
#pragma unroll
        for (int o = 1; o < 64; o <<= 1) dot += __shfl_xor(dot, o, 64);
        if (lane == 0 && (a & 511) < cc && pc > 0) {
            float lse = logf(row_sumexp[a]);
            lsum += (TEMP_INV * dot - (float)pc * lse) / (float)pc;
            vc += 1.0f;
        }
    }

    __shared__ float wls[4], wvc[4];
    if (lane == 0) { wls[wv] = lsum; wvc[wv] = vc; }
    __syncthreads();
    if (t == 0) {
        atomicAdd(&facc[0], wls[0] + wls[1] + wls[2] + wls[3]);
        atomicAdd(&facc[1], wvc[0] + wvc[1] + wvc[2] + wvc[3]);
        __threadfence();
        unsigned d = atomicAdd((unsigned*)done_cnt, 1u);
        if (d == 639u) {   // last block: totals are globally visible via atomics
            __threadfence();
            float L = atomicAdd(&facc[0], 0.0f);
            float V = atomicAdd(&facc[1], 0.0f);
            out[0] = -L / fmaxf(V, 1.0f);
        }
    }
}

// ---------------- launch ----------------
extern "C" void kernel_launch(void* const* d_in, const int* in_sizes, int n_in,
                              void* d_out, int out_size, void* d_ws, size_t ws_size,
                              hipStream_t stream) {
    const float* main_proj = (const float*)d_in[0];
    const int*   main_gt   = (const int*)d_in[1];
    const float* aux_proj  = (const float*)d_in[2];
    const int*   aux_gt    = (const int*)d_in[3];
    const float* bank      = (const float*)d_in[4];
    float* out = (float*)d_out;

    char* ws = (char*)d_ws;
    int*   labels     = (int*)ws;                    // 524288 B (dead after k_write)
    int*   hist       = (int*)(ws + 524288);         // 40960 B
    int*   row2pix    = (int*)(ws + 565248);         // 40960 B used (region is 524288 B)
    int*   c_valid    = (int*)(ws + 1089536);        // 40960 B
    float* zreg       = (float*)(ws + 1130496);      // 61952 B zero region
    float* row_sumexp = zreg;
    float* S          = zreg + 10240;
    int*   pcnt       = (int*)(zreg + 15360);
    float* facc       = zreg + 15380;
    int*   done_cnt   = (int*)(zreg + 15382);
    int*   counts     = (int*)(ws + 1192448);        // 256 B (written by k_write, no pre-zero)
    short* anchorsB   = (short*)(ws + 11678464);     // 5242880 B
    short* contrasB   = (short*)(ws + 16921344);     // 5242880 B (end 22164224)

    k_hist<<<512, 256, 0, stream>>>(main_gt, aux_gt, labels, hist, row2pix, zreg);
    k_write<<<512, 256, 0, stream>>>(labels, hist, row2pix, counts);
    k_nbc<<<AROWS / 16, 256, 0, stream>>>(main_proj, aux_proj, row2pix, bank, counts,
                                          anchorsB, contrasB, c_valid, S, pcnt);
    dim3 grid(AROWS / 128, AROWS / 256);
    k_score<<<grid, 512, 0, stream>>>(anchorsB, contrasB, c_valid, row_sumexp);
    k_fin<<<AROWS / 16, 256, 0, stream>>>(anchorsB, S, counts, pcnt, row_sumexp,
                                          facc, done_cnt, out);
}